// Round 1
// baseline (802.937 us; speedup 1.0000x reference)
//
#include <hip/hip_runtime.h>
#include <hip/hip_bf16.h>

typedef __attribute__((ext_vector_type(8))) __bf16 bf16x8;
typedef __attribute__((ext_vector_type(4))) float f32x4;
typedef __hip_bfloat16 bf16t;

#define DEV __device__ __forceinline__

DEV void async16(const void* g, void* l) {
    __builtin_amdgcn_global_load_lds(
        (const __attribute__((address_space(1))) unsigned int*)g,
        (__attribute__((address_space(3))) unsigned int*)l,
        16, 0, 0);
}

DEV float wave_sum(float s) {
#pragma unroll
    for (int o = 32; o > 0; o >>= 1) s += __shfl_xor(s, o);
    return s;
}

DEV float wave_max(float s) {
#pragma unroll
    for (int o = 32; o > 0; o >>= 1) s = fmaxf(s, __shfl_xor(s, o));
    return s;
}

// ---------------- cast fp32 -> bf16 (4 elems/thread) ----------------
__global__ void cast_bf16_kernel(const float* __restrict__ in, bf16t* __restrict__ out, int n4) {
    int i = blockIdx.x * blockDim.x + threadIdx.x;
    if (i >= n4) return;
    f32x4 v = *(const f32x4*)(in + (size_t)i * 4);
    bf16t* o = out + (size_t)i * 4;
    o[0] = __float2bfloat16(v.x);
    o[1] = __float2bfloat16(v.y);
    o[2] = __float2bfloat16(v.z);
    o[3] = __float2bfloat16(v.w);
}

// ---------------- transpose fp32 [R][Ccols] -> bf16 [RP][R], zero-pad rows >= Ccols ----------------
__global__ void transpose_bf16_kernel(const float* __restrict__ in, bf16t* __restrict__ out,
                                      int R, int Ccols, int RP) {
    int idx = blockIdx.x * blockDim.x + threadIdx.x;
    if (idx >= RP * R) return;
    int n = idx / R;
    int k = idx - n * R;
    float v = (n < Ccols) ? in[(size_t)k * Ccols + n] : 0.0f;
    out[idx] = __float2bfloat16(v);
}

// ---------------- bf16 MFMA GEMM: C[M][N] = A[M][K] @ BT[N][K]^T + bias ----------------
// 128x128 tile, BK=32, 256 threads (4 waves, 2x2 of 64x64), XOR-swizzled LDS.
template <bool LRELU, bool OUTF32, bool NGUARD>
__global__ __launch_bounds__(256) void gemm_bt(
    const bf16t* __restrict__ A, const bf16t* __restrict__ BT,
    const float* __restrict__ bias,
    float* __restrict__ Cf, bf16t* __restrict__ Cb,
    int M, int N, int K) {
    __shared__ __align__(16) char ldsA[8192];
    __shared__ __align__(16) char ldsB[8192];

    const int tid = threadIdx.x;
    const int lane = tid & 63;
    const int w = tid >> 6;
    const int wr = w >> 1, wc = w & 1;
    const int brow = blockIdx.y * 128;
    const int bcol = blockIdx.x * 128;

    f32x4 acc[4][4] = {};

    // staging: 512 16B chunks; thread handles chunk tid and tid+256.
    // LDS linear pos p = q*16 -> row r = p/64, chunk c = (p/16)&3.
    // Data at (r,c) = global[row r][k0 + ((c ^ ((r>>1)&3))*8) .. +8]
    const int q0 = tid, q1 = tid + 256;
    const int r0 = q0 >> 2, c0 = q0 & 3;
    const int r1 = q1 >> 2, c1 = q1 & 3;
    const int ka0 = ((c0 ^ ((r0 >> 1) & 3)) << 3);
    const int ka1 = ((c1 ^ ((r1 >> 1) & 3)) << 3);

    const bf16t* aSrc0 = A + (size_t)(brow + r0) * K + ka0;
    const bf16t* aSrc1 = A + (size_t)(brow + r1) * K + ka1;
    const bf16t* bSrc0 = BT + (size_t)(bcol + r0) * K + ka0;
    const bf16t* bSrc1 = BT + (size_t)(bcol + r1) * K + ka1;
    char* ldA0 = ldsA + w * 1024;
    char* ldA1 = ldsA + 4096 + w * 1024;
    char* ldB0 = ldsB + w * 1024;
    char* ldB1 = ldsB + 4096 + w * 1024;

    // fragment read addresses (swizzled)
    const int j = lane >> 4, rl = lane & 15;
    const char* aAddr[4];
    const char* bAddr[4];
#pragma unroll
    for (int mi = 0; mi < 4; ++mi) {
        int row = wr * 64 + mi * 16 + rl;
        aAddr[mi] = ldsA + row * 64 + ((j ^ ((row >> 1) & 3)) << 4);
    }
#pragma unroll
    for (int ni = 0; ni < 4; ++ni) {
        int row = wc * 64 + ni * 16 + rl;
        bAddr[ni] = ldsB + row * 64 + ((j ^ ((row >> 1) & 3)) << 4);
    }

    for (int k0 = 0; k0 < K; k0 += 32) {
        __syncthreads();
        async16(aSrc0 + k0, ldA0);
        async16(aSrc1 + k0, ldA1);
        async16(bSrc0 + k0, ldB0);
        async16(bSrc1 + k0, ldB1);
        __syncthreads();

        bf16x8 af[4], bfr[4];
#pragma unroll
        for (int mi = 0; mi < 4; ++mi) af[mi] = *(const bf16x8*)aAddr[mi];
#pragma unroll
        for (int ni = 0; ni < 4; ++ni) bfr[ni] = *(const bf16x8*)bAddr[ni];
#pragma unroll
        for (int mi = 0; mi < 4; ++mi)
#pragma unroll
            for (int ni = 0; ni < 4; ++ni)
                acc[mi][ni] = __builtin_amdgcn_mfma_f32_16x16x32_bf16(af[mi], bfr[ni], acc[mi][ni], 0, 0, 0);
    }

    // epilogue: C row=(lane>>4)*4+reg, col=lane&15 within each 16x16 fragment
#pragma unroll
    for (int mi = 0; mi < 4; ++mi) {
#pragma unroll
        for (int ni = 0; ni < 4; ++ni) {
            int col = bcol + wc * 64 + ni * 16 + (lane & 15);
            if (!NGUARD || col < N) {
                float bv = bias[col];
#pragma unroll
                for (int r = 0; r < 4; ++r) {
                    int row = brow + wr * 64 + mi * 16 + (lane >> 4) * 4 + r;
                    float v = acc[mi][ni][r] + bv;
                    if (LRELU) v = v > 0.0f ? v : 0.01f * v;
                    if (OUTF32) Cf[(size_t)row * N + col] = v;
                    else        Cb[(size_t)row * N + col] = __float2bfloat16(v);
                }
            }
        }
    }
}

// ---------------- emb row L2-normalize: fp32 out + bf16 copy ----------------
__global__ void normalize_kernel(const float* __restrict__ raw, float* __restrict__ outf,
                                 bf16t* __restrict__ outb) {
    int row = blockIdx.x * 4 + (threadIdx.x >> 6);
    int lane = threadIdx.x & 63;
    f32x4 v = *(const f32x4*)(raw + (size_t)row * 256 + lane * 4);
    float s = wave_sum(v.x * v.x + v.y * v.y + v.z * v.z + v.w * v.w);
    float rn = 1.0f / sqrtf(s);
    f32x4 o = v * rn;
    *(f32x4*)(outf + (size_t)row * 256 + lane * 4) = o;
    bf16t* ob = outb + (size_t)row * 256 + lane * 4;
    ob[0] = __float2bfloat16(o.x);
    ob[1] = __float2bfloat16(o.y);
    ob[2] = __float2bfloat16(o.z);
    ob[3] = __float2bfloat16(o.w);
}

// ---------------- prototypes: normalize rows, sum(P*P), softmax priors ----------------
__global__ void proto_kernel(const float* __restrict__ proto, const float* __restrict__ prior,
                             float* __restrict__ Pn, float* __restrict__ sp, float* __restrict__ priors) {
    int w = threadIdx.x >> 6, lane = threadIdx.x & 63;
    for (int r = w; r < 20; r += 4) {
        f32x4 v = *(const f32x4*)(proto + (size_t)r * 256 + lane * 4);
        float s = wave_sum(v.x * v.x + v.y * v.y + v.z * v.z + v.w * v.w);
        float rn = 1.0f / sqrtf(s);
        f32x4 p = v * rn;
        *(f32x4*)(Pn + (size_t)r * 256 + lane * 4) = p;
        float s2 = wave_sum(p.x * p.x + p.y * p.y + p.z * p.z + p.w * p.w);
        if (lane == 0) sp[r] = s2;
    }
    if (threadIdx.x < 64) {
        float pv = (lane < 20) ? prior[lane] : -1e30f;
        float m = wave_max(pv);
        float e = (lane < 20) ? expf(pv / m) : 0.0f;
        float ssum = wave_sum(e);
        if (lane < 20) priors[lane] = e / ssum;
    }
}

// ---------------- scores: d2 -> exp -> *prior -> [bg, proba...] ----------------
__global__ void scores_kernel(const float* __restrict__ emb, const float* __restrict__ Pn,
                              const float* __restrict__ sp, const float* __restrict__ priors,
                              const float* __restrict__ sig, float* __restrict__ out) {
    int row = blockIdx.x * 4 + (threadIdx.x >> 6);
    int lane = threadIdx.x & 63;
    f32x4 e = *(const f32x4*)(emb + (size_t)row * 256 + lane * 4);
    float se = wave_sum(e.x * e.x + e.y * e.y + e.z * e.z + e.w * e.w);
    float keep = 0.0f, mx = -1.0f;
    for (int k = 0; k < 20; ++k) {
        f32x4 p = *(const f32x4*)(Pn + (size_t)k * 256 + lane * 4);
        float d = wave_sum(e.x * p.x + e.y * p.y + e.z * p.z + e.w * p.w);
        float d2 = se + sp[k] - 2.0f * d;
        float sgv = sig[k];
        float pr = expf(-d2 / (2.0f * sgv * sgv)) * priors[k];
        mx = fmaxf(mx, pr);
        if (lane == k + 1) keep = pr;
    }
    if (lane == 0) keep = 1.0f - mx;
    if (lane < 21) out[(size_t)row * 21 + lane] = keep;
}

extern "C" void kernel_launch(void* const* d_in, const int* in_sizes, int n_in,
                              void* d_out, int out_size, void* d_ws, size_t ws_size,
                              hipStream_t stream) {
    const float* x     = (const float*)d_in[0];
    const float* proto = (const float*)d_in[1];
    const float* sig   = (const float*)d_in[2];
    const float* prior = (const float*)d_in[3];
    const float* W1c = (const float*)d_in[4];
    const float* b1c = (const float*)d_in[5];
    const float* W2c = (const float*)d_in[6];
    const float* b2c = (const float*)d_in[7];
    const float* W1b = (const float*)d_in[8];
    const float* b1b = (const float*)d_in[9];
    const float* W2b = (const float*)d_in[10];
    const float* b2b = (const float*)d_in[11];
    const float* Wr1 = (const float*)d_in[12];
    const float* br1 = (const float*)d_in[13];
    const float* Wr2 = (const float*)d_in[14];
    const float* br2 = (const float*)d_in[15];

    float* out = (float*)d_out;
    float* out_scores = out;                  // [8192,21]
    float* out_bbox   = out + 172032;         // [8192,84]
    float* out_emb    = out + 860160;         // [8192,256]
    float* out_rec    = out + 2957312;        // [8192,12544]

    char* ws = (char*)d_ws;
    size_t off = 0;
    auto alloc = [&](size_t b) { char* p = ws + off; off += (b + 255) & ~(size_t)255; return p; };
    bf16t* xb     = (bf16t*)alloc(8192ull * 1024 * 2);
    bf16t* w1ct   = (bf16t*)alloc(1024ull * 1024 * 2);
    bf16t* w1bt   = (bf16t*)alloc(1024ull * 1024 * 2);
    bf16t* w2ct   = (bf16t*)alloc(256ull * 1024 * 2);
    bf16t* w2bt   = (bf16t*)alloc(128ull * 1024 * 2);
    bf16t* wr1t   = (bf16t*)alloc(512ull * 256 * 2);
    bf16t* wr2t   = (bf16t*)alloc(12544ull * 512 * 2);
    bf16t* hc     = (bf16t*)alloc(8192ull * 1024 * 2);
    bf16t* hb     = (bf16t*)alloc(8192ull * 1024 * 2);
    float* embraw = (float*)alloc(8192ull * 256 * 4);
    bf16t* embb   = (bf16t*)alloc(8192ull * 256 * 2);
    bf16t* rech   = (bf16t*)alloc(8192ull * 512 * 2);
    float* Pn     = (float*)alloc(20 * 256 * 4);
    float* spv    = (float*)alloc(20 * 4);
    float* priors = (float*)alloc(20 * 4);
    (void)ws_size; (void)in_sizes; (void)n_in; (void)out_size;

    // prep
    cast_bf16_kernel<<<8192, 256, 0, stream>>>(x, xb, 8192 * 1024 / 4);
    transpose_bf16_kernel<<<4096, 256, 0, stream>>>(W1c, w1ct, 1024, 1024, 1024);
    transpose_bf16_kernel<<<4096, 256, 0, stream>>>(W1b, w1bt, 1024, 1024, 1024);
    transpose_bf16_kernel<<<1024, 256, 0, stream>>>(W2c, w2ct, 1024, 256, 256);
    transpose_bf16_kernel<<<512, 256, 0, stream>>>(W2b, w2bt, 1024, 84, 128);
    transpose_bf16_kernel<<<512, 256, 0, stream>>>(Wr1, wr1t, 256, 512, 512);
    transpose_bf16_kernel<<<25088, 256, 0, stream>>>(Wr2, wr2t, 512, 12544, 12544);

    // cls tower
    gemm_bt<true, false, false><<<dim3(8, 64), 256, 0, stream>>>(xb, w1ct, b1c, nullptr, hc, 8192, 1024, 1024);
    // bbox tower
    gemm_bt<true, false, false><<<dim3(8, 64), 256, 0, stream>>>(xb, w1bt, b1b, nullptr, hb, 8192, 1024, 1024);
    // emb raw
    gemm_bt<false, true, false><<<dim3(2, 64), 256, 0, stream>>>(hc, w2ct, b2c, embraw, nullptr, 8192, 256, 1024);
    // bbox out
    gemm_bt<false, true, true><<<dim3(1, 64), 256, 0, stream>>>(hb, w2bt, b2b, out_bbox, nullptr, 8192, 84, 1024);
    // normalize emb
    normalize_kernel<<<2048, 256, 0, stream>>>(embraw, out_emb, embb);
    // prototypes + priors
    proto_kernel<<<1, 256, 0, stream>>>(proto, prior, Pn, spv, priors);
    // scores
    scores_kernel<<<2048, 256, 0, stream>>>(out_emb, Pn, spv, priors, sig, out_scores);
    // reconstruction tower
    gemm_bt<true, false, false><<<dim3(4, 64), 256, 0, stream>>>(embb, wr1t, br1, nullptr, rech, 8192, 512, 256);
    gemm_bt<false, true, false><<<dim3(98, 64), 256, 0, stream>>>(rech, wr2t, br2, out_rec, nullptr, 8192, 12544, 512);
}

// Round 5
// 763.766 us; speedup vs baseline: 1.0513x; 1.0513x over previous
//
#include <hip/hip_runtime.h>
#include <hip/hip_bf16.h>

typedef __attribute__((ext_vector_type(8))) __bf16 bf16x8;
typedef __attribute__((ext_vector_type(4))) float f32x4;
typedef __hip_bfloat16 bf16t;

#define DEV __device__ __forceinline__

DEV void async16(const void* g, void* l) {
    __builtin_amdgcn_global_load_lds(
        (const __attribute__((address_space(1))) unsigned int*)g,
        (__attribute__((address_space(3))) unsigned int*)l,
        16, 0, 0);
}

DEV float wave_sum(float s) {
#pragma unroll
    for (int o = 32; o > 0; o >>= 1) s += __shfl_xor(s, o);
    return s;
}

DEV float wave_max(float s) {
#pragma unroll
    for (int o = 32; o > 0; o >>= 1) s = fmaxf(s, __shfl_xor(s, o));
    return s;
}

// ---------------- cast fp32 -> bf16 (8 elems/thread) ----------------
__global__ void cast_bf16_kernel(const float* __restrict__ in, bf16t* __restrict__ out, int n8) {
    int i = blockIdx.x * blockDim.x + threadIdx.x;
    if (i >= n8) return;
    f32x4 a = *(const f32x4*)(in + (size_t)i * 8);
    f32x4 b = *(const f32x4*)(in + (size_t)i * 8 + 4);
    union { bf16t h[8]; uint4 u; } r;
    r.h[0] = __float2bfloat16(a.x); r.h[1] = __float2bfloat16(a.y);
    r.h[2] = __float2bfloat16(a.z); r.h[3] = __float2bfloat16(a.w);
    r.h[4] = __float2bfloat16(b.x); r.h[5] = __float2bfloat16(b.y);
    r.h[6] = __float2bfloat16(b.z); r.h[7] = __float2bfloat16(b.w);
    *(uint4*)(out + (size_t)i * 8) = r.u;
}

// ---------------- LDS-tiled transpose: in fp32 [R][C] -> out bf16 [CP][R] ----------------
// out[n][k] = (n < C) ? in[k][n] : 0.   Grid: ( (CP+31)/32, (R+31)/32 ), block 256.
__global__ void transpose_tile_kernel(const float* __restrict__ in, bf16t* __restrict__ out,
                                      int R, int C, int CP) {
    __shared__ float tile[32][33];
    const int nt = blockIdx.x * 32;
    const int kt = blockIdx.y * 32;
    const int tx = threadIdx.x & 31;
    const int ty = threadIdx.x >> 5;  // 0..7
#pragma unroll
    for (int i = 0; i < 4; ++i) {
        int k = kt + ty + i * 8;
        int n = nt + tx;
        tile[ty + i * 8][tx] = (k < R && n < C) ? in[(size_t)k * C + n] : 0.0f;
    }
    __syncthreads();
#pragma unroll
    for (int i = 0; i < 4; ++i) {
        int n = nt + ty + i * 8;
        int k = kt + tx;
        if (n < CP && k < R)
            out[(size_t)n * R + k] = __float2bfloat16(tile[tx][ty + i * 8]);
    }
}

// ---------------- bf16 MFMA GEMM: C[M][N] = A[M][K](lda) @ BT[N][K]^T + bias ----------------
// 128x128 tile, BK=32, 256 threads (4 waves, 2x2 of 64x64), XOR-swizzled LDS.
template <bool LRELU, bool OUTF32, bool NGUARD>
__global__ __launch_bounds__(256) void gemm_bt(
    const bf16t* __restrict__ A, int lda, const bf16t* __restrict__ BT,
    const float* __restrict__ bias0, const float* __restrict__ bias1, int nsplit,
    float* __restrict__ Cf, bf16t* __restrict__ Cb,
    int M, int N, int K) {
    __shared__ __align__(16) char ldsA[8192];
    __shared__ __align__(16) char ldsB[8192];

    const int tid = threadIdx.x;
    const int lane = tid & 63;
    const int w = tid >> 6;
    const int wr = w >> 1, wc = w & 1;
    const int brow = blockIdx.y * 128;
    const int bcol = blockIdx.x * 128;

    f32x4 acc[4][4] = {};

    const int q0 = tid, q1 = tid + 256;
    const int r0 = q0 >> 2, c0 = q0 & 3;
    const int r1 = q1 >> 2, c1 = q1 & 3;
    const int ka0 = ((c0 ^ ((r0 >> 1) & 3)) << 3);
    const int ka1 = ((c1 ^ ((r1 >> 1) & 3)) << 3);

    const bf16t* aSrc0 = A + (size_t)(brow + r0) * lda + ka0;
    const bf16t* aSrc1 = A + (size_t)(brow + r1) * lda + ka1;
    const bf16t* bSrc0 = BT + (size_t)(bcol + r0) * K + ka0;
    const bf16t* bSrc1 = BT + (size_t)(bcol + r1) * K + ka1;
    char* ldA0 = ldsA + w * 1024;
    char* ldA1 = ldsA + 4096 + w * 1024;
    char* ldB0 = ldsB + w * 1024;
    char* ldB1 = ldsB + 4096 + w * 1024;

    const int j = lane >> 4, rl = lane & 15;
    const char* aAddr[4];
    const char* bAddr[4];
#pragma unroll
    for (int mi = 0; mi < 4; ++mi) {
        int row = wr * 64 + mi * 16 + rl;
        aAddr[mi] = ldsA + row * 64 + ((j ^ ((row >> 1) & 3)) << 4);
    }
#pragma unroll
    for (int ni = 0; ni < 4; ++ni) {
        int row = wc * 64 + ni * 16 + rl;
        bAddr[ni] = ldsB + row * 64 + ((j ^ ((row >> 1) & 3)) << 4);
    }

    for (int k0 = 0; k0 < K; k0 += 32) {
        __syncthreads();
        async16(aSrc0 + k0, ldA0);
        async16(aSrc1 + k0, ldA1);
        async16(bSrc0 + k0, ldB0);
        async16(bSrc1 + k0, ldB1);
        __syncthreads();

        bf16x8 af[4], bfr[4];
#pragma unroll
        for (int mi = 0; mi < 4; ++mi) af[mi] = *(const bf16x8*)aAddr[mi];
#pragma unroll
        for (int ni = 0; ni < 4; ++ni) bfr[ni] = *(const bf16x8*)bAddr[ni];
#pragma unroll
        for (int mi = 0; mi < 4; ++mi)
#pragma unroll
            for (int ni = 0; ni < 4; ++ni)
                acc[mi][ni] = __builtin_amdgcn_mfma_f32_16x16x32_bf16(af[mi], bfr[ni], acc[mi][ni], 0, 0, 0);
    }

#pragma unroll
    for (int mi = 0; mi < 4; ++mi) {
#pragma unroll
        for (int ni = 0; ni < 4; ++ni) {
            int col = bcol + wc * 64 + ni * 16 + (lane & 15);
            if (!NGUARD || col < N) {
                float bv = (col < nsplit) ? bias0[col] : bias1[col - nsplit];
#pragma unroll
                for (int r = 0; r < 4; ++r) {
                    int row = brow + wr * 64 + mi * 16 + (lane >> 4) * 4 + r;
                    float v = acc[mi][ni][r] + bv;
                    if (LRELU) v = v > 0.0f ? v : 0.01f * v;
                    if (OUTF32) Cf[(size_t)row * N + col] = v;
                    else        Cb[(size_t)row * N + col] = __float2bfloat16(v);
                }
            }
        }
    }
}

// ---------------- prototypes: normalize rows, sum(P*P), softmax priors ----------------
__global__ void proto_kernel(const float* __restrict__ proto, const float* __restrict__ prior,
                             float* __restrict__ Pn, float* __restrict__ sp, float* __restrict__ priors) {
    int w = threadIdx.x >> 6, lane = threadIdx.x & 63;
    for (int r = w; r < 20; r += 4) {
        f32x4 v = *(const f32x4*)(proto + (size_t)r * 256 + lane * 4);
        float s = wave_sum(v.x * v.x + v.y * v.y + v.z * v.z + v.w * v.w);
        float rn = 1.0f / sqrtf(s);
        f32x4 p = v * rn;
        *(f32x4*)(Pn + (size_t)r * 256 + lane * 4) = p;
        float s2 = wave_sum(p.x * p.x + p.y * p.y + p.z * p.z + p.w * p.w);
        if (lane == 0) sp[r] = s2;
    }
    if (threadIdx.x < 64) {
        float pv = (lane < 20) ? prior[lane] : -1e30f;
        float m = wave_max(pv);
        float e = (lane < 20) ? expf(pv / m) : 0.0f;
        float ssum = wave_sum(e);
        if (lane < 20) priors[lane] = e / ssum;
    }
}

// ---------------- fused: L2-normalize emb row + write fp32/bf16 + RBF scores ----------------
__global__ void norm_scores_kernel(const float* __restrict__ raw, const float* __restrict__ Pn,
                                   const float* __restrict__ sp, const float* __restrict__ priors,
                                   const float* __restrict__ sig,
                                   float* __restrict__ outf, bf16t* __restrict__ outb,
                                   float* __restrict__ scores) {
    int row = blockIdx.x * 4 + (threadIdx.x >> 6);
    int lane = threadIdx.x & 63;
    f32x4 v = *(const f32x4*)(raw + (size_t)row * 256 + lane * 4);
    float s = wave_sum(v.x * v.x + v.y * v.y + v.z * v.z + v.w * v.w);
    float rn = 1.0f / sqrtf(s);
    f32x4 e = v * rn;
    *(f32x4*)(outf + (size_t)row * 256 + lane * 4) = e;
    union { bf16t h[4]; uint2 u; } rb;
    rb.h[0] = __float2bfloat16(e.x); rb.h[1] = __float2bfloat16(e.y);
    rb.h[2] = __float2bfloat16(e.z); rb.h[3] = __float2bfloat16(e.w);
    *(uint2*)(outb + (size_t)row * 256 + lane * 4) = rb.u;

    float se = s * rn * rn;  // == sum(e*e), ~1
    float keep = 0.0f, mx = -1.0f;
    for (int k = 0; k < 20; ++k) {
        f32x4 p = *(const f32x4*)(Pn + (size_t)k * 256 + lane * 4);
        float d = wave_sum(e.x * p.x + e.y * p.y + e.z * p.z + e.w * p.w);
        float d2 = se + sp[k] - 2.0f * d;
        float sgv = sig[k];
        float pr = expf(-d2 / (2.0f * sgv * sgv)) * priors[k];
        mx = fmaxf(mx, pr);
        if (lane == k + 1) keep = pr;
    }
    if (lane == 0) keep = 1.0f - mx;
    if (lane < 21) scores[(size_t)row * 21 + lane] = keep;
}

extern "C" void kernel_launch(void* const* d_in, const int* in_sizes, int n_in,
                              void* d_out, int out_size, void* d_ws, size_t ws_size,
                              hipStream_t stream) {
    const float* x     = (const float*)d_in[0];
    const float* proto = (const float*)d_in[1];
    const float* sig   = (const float*)d_in[2];
    const float* prior = (const float*)d_in[3];
    const float* W1c = (const float*)d_in[4];
    const float* b1c = (const float*)d_in[5];
    const float* W2c = (const float*)d_in[6];
    const float* b2c = (const float*)d_in[7];
    const float* W1b = (const float*)d_in[8];
    const float* b1b = (const float*)d_in[9];
    const float* W2b = (const float*)d_in[10];
    const float* b2b = (const float*)d_in[11];
    const float* Wr1 = (const float*)d_in[12];
    const float* br1 = (const float*)d_in[13];
    const float* Wr2 = (const float*)d_in[14];
    const float* br2 = (const float*)d_in[15];

    float* out = (float*)d_out;
    float* out_scores = out;                  // [8192,21]
    float* out_bbox   = out + 172032;         // [8192,84]
    float* out_emb    = out + 860160;         // [8192,256]
    float* out_rec    = out + 2957312;        // [8192,12544]

    char* ws = (char*)d_ws;
    size_t off = 0;
    auto alloc = [&](size_t b) { char* p = ws + off; off += (b + 255) & ~(size_t)255; return p; };
    bf16t* xb     = (bf16t*)alloc(8192ull * 1024 * 2);
    bf16t* w1t    = (bf16t*)alloc(2048ull * 1024 * 2);   // [W1c^T ; W1b^T] rows 0..1023 / 1024..2047
    bf16t* w2ct   = (bf16t*)alloc(256ull * 1024 * 2);
    bf16t* w2bt   = (bf16t*)alloc(128ull * 1024 * 2);
    bf16t* wr1t   = (bf16t*)alloc(512ull * 256 * 2);
    bf16t* wr2t   = (bf16t*)alloc(12544ull * 512 * 2);
    bf16t* hcb    = (bf16t*)alloc(8192ull * 2048 * 2);   // [hc | hb]
    float* embraw = (float*)alloc(8192ull * 256 * 4);
    bf16t* embb   = (bf16t*)alloc(8192ull * 256 * 2);
    bf16t* rech   = (bf16t*)alloc(8192ull * 512 * 2);
    float* Pn     = (float*)alloc(20 * 256 * 4);
    float* spv    = (float*)alloc(20 * 4);
    float* priors = (float*)alloc(20 * 4);
    (void)ws_size; (void)in_sizes; (void)n_in; (void)out_size;

    // prep (all independent)
    cast_bf16_kernel<<<4096, 256, 0, stream>>>(x, xb, 8192 * 1024 / 8);
    transpose_tile_kernel<<<dim3(32, 32), 256, 0, stream>>>(W1c, w1t, 1024, 1024, 1024);
    transpose_tile_kernel<<<dim3(32, 32), 256, 0, stream>>>(W1b, w1t + 1024ull * 1024, 1024, 1024, 1024);
    transpose_tile_kernel<<<dim3(8, 32), 256, 0, stream>>>(W2c, w2ct, 1024, 256, 256);
    transpose_tile_kernel<<<dim3(4, 32), 256, 0, stream>>>(W2b, w2bt, 1024, 84, 128);
    transpose_tile_kernel<<<dim3(16, 8), 256, 0, stream>>>(Wr1, wr1t, 256, 512, 512);
    transpose_tile_kernel<<<dim3(392, 16), 256, 0, stream>>>(Wr2, wr2t, 512, 12544, 12544);
    proto_kernel<<<1, 256, 0, stream>>>(proto, prior, Pn, spv, priors);

    // fused cls+bbox hidden: [8192,2048] = xb @ [W1c;W1b]^T, LeakyReLU, bf16
    gemm_bt<true, false, false><<<dim3(16, 64), 256, 0, stream>>>(
        xb, 1024, w1t, b1c, b1b, 1024, nullptr, hcb, 8192, 2048, 1024);
    // emb raw: hc part (cols 0..1023)
    gemm_bt<false, true, false><<<dim3(2, 64), 256, 0, stream>>>(
        hcb, 2048, w2ct, b2c, b2c, 256, embraw, nullptr, 8192, 256, 1024);
    // bbox out: hb part (cols 1024..2047)
    gemm_bt<false, true, true><<<dim3(1, 64), 256, 0, stream>>>(
        hcb + 1024, 2048, w2bt, b2b, b2b, 128, out_bbox, nullptr, 8192, 84, 1024);
    // normalize + scores fused
    norm_scores_kernel<<<2048, 256, 0, stream>>>(embraw, Pn, spv, priors, sig, out_emb, embb, out_scores);
    // reconstruction tower
    gemm_bt<true, false, false><<<dim3(4, 64), 256, 0, stream>>>(
        embb, 256, wr1t, br1, br1, 512, nullptr, rech, 8192, 512, 256);
    gemm_bt<false, true, false><<<dim3(98, 64), 256, 0, stream>>>(
        rech, 512, wr2t, br2, br2, 12544, out_rec, nullptr, 8192, 12544, 512);
}